// Round 1
// 1470.436 us; speedup vs baseline: 1.1616x; 1.1616x over previous
//
#include <hip/hip_runtime.h>
#include <math.h>

// ---------------------------------------------------------------------------
// Criss-Cross-Attention pipeline, fp32 correctness-first implementation.
// Shapes: x (4,256,256,256); conv 4x4 s2 VALID -> xd (4,256,127,127)
// q,k: (4,32,127,127); v: (4,256,127,127); a = resize(attn_map) (4,64,127,127)
// scores: per (b,i,j) 254-vector = [col(l=0..126), row(m=0..126)]
// S = softmax( softmax(e_qk) * softmax(e_aa) ); out = attH.v + attW.v
// final: gamma * (resize(outH)+resize(outW)) + x
//
// Workspace layout (floats), planes padded to Ppad=16132 for float4 alignment:
//   R0 [0, PL)            : xd  -> Saa -> outW      (lifetimes disjoint)
//   R1 [PL, 2PL)          : v
//   R2 [2PL, 2PL+SL)      : Sqk -> S (in-place)
//   R3 [2PL+SL, 3PL+SL)   : q | k | a  -> outH^T    (lifetimes disjoint)
//   R4 [3PL+SL, 4PL+SL)   : v^T (per-plane transposed)
// total = 4*PL + SL = 82,463,736 floats = ~330 MB   (assumes ws_size >= this)
// ---------------------------------------------------------------------------

static constexpr int Bn   = 4;
static constexpr int Cn   = 256;
static constexpr int Hn   = 256;
static constexpr int Wn   = 256;
static constexpr int CAn  = 64;
static constexpr int CQn  = 32;
static constexpr int hn   = 127;
static constexpr int wn   = 127;
static constexpr int Pn   = hn * wn;   // 16129
static constexpr int Ppad = 16132;     // padded plane stride (mult of 4)
static constexpr int Ln   = 254;       // concat score length

__device__ __forceinline__ float wred_max(float v) {
#pragma unroll
  for (int o = 32; o > 0; o >>= 1) v = fmaxf(v, __shfl_xor(v, o, 64));
  return v;
}
__device__ __forceinline__ float wred_sum(float v) {
#pragma unroll
  for (int o = 32; o > 0; o >>= 1) v += __shfl_xor(v, o, 64);
  return v;
}

// --- depthwise 4x4 stride-2 conv: x (B,C,256,256) -> xd (B,C,127,127) -------
__global__ __launch_bounds__(256) void k_conv(const float* __restrict__ x,
                                              const float* __restrict__ wd,
                                              float* __restrict__ xd) {
  int p  = blockIdx.x * 256 + threadIdx.x;
  int bc = blockIdx.y;  // b*Cn + c
  if (p >= Pn) return;
  int oy = p / wn, ox = p - oy * wn;
  int c  = bc & (Cn - 1);
  const float* wp = wd + c * 16;
  const float* xp = x + (size_t)bc * (Hn * Wn) + (2 * oy) * Wn + 2 * ox;
  float s = 0.f;
#pragma unroll
  for (int ky = 0; ky < 4; ky++)
#pragma unroll
    for (int kx = 0; kx < 4; kx++)
      s = fmaf(xp[ky * Wn + kx], wp[ky * 4 + kx], s);
  xd[(size_t)bc * Ppad + p] = s;
}

// --- bilinear resize attn_map (B,64,256,256) -> a (B,64,127,127) ------------
__global__ __launch_bounds__(256) void k_resize_a(const float* __restrict__ src,
                                                  float* __restrict__ dst) {
  int idx = blockIdx.x * 256 + threadIdx.x;
  if (idx >= Bn * CAn * Pn) return;
  int p = idx % Pn, bc = idx / Pn;
  int i = p / wn, j = p - i * wn;
  float fy = i * (255.0f / 126.0f);
  float fx = j * (255.0f / 126.0f);
  int y0 = min((int)fy, Hn - 1), x0 = min((int)fx, Wn - 1);
  int y1 = min(y0 + 1, Hn - 1), x1 = min(x0 + 1, Wn - 1);
  float wy = fy - y0, wx = fx - x0;
  const float* sp = src + (size_t)bc * (Hn * Wn);
  float v00 = sp[y0 * Wn + x0], v01 = sp[y0 * Wn + x1];
  float v10 = sp[y1 * Wn + x0], v11 = sp[y1 * Wn + x1];
  dst[(size_t)bc * Ppad + p] =
      (v00 * (1.f - wy) + v10 * wy) * (1.f - wx) +
      (v01 * (1.f - wy) + v11 * wy) * wx;
}

// --- out[b,o,p] = sum_c W[o,c]*xd[b,c,p] + bias[o]  (tile 64o x 128p) -------
__global__ __launch_bounds__(256) void k_gemm(const float* __restrict__ Wt,
                                              const float* __restrict__ bias,
                                              const float* __restrict__ xd,
                                              float* __restrict__ out, int O) {
  __shared__ float xs[16][128];
  __shared__ float wsT[16][64];
  int p0 = blockIdx.x * 128, o0 = blockIdx.y * 64, b = blockIdx.z;
  int tid = threadIdx.x;
  int tp = tid & 31, to = tid >> 5;
  const float* xb = xd + (size_t)b * Cn * Ppad;
  float acc[8][4] = {};
  for (int c0 = 0; c0 < Cn; c0 += 16) {
#pragma unroll
    for (int u = 0; u < 2; u++) {
      int idx = tid + u * 256;               // 512 float4s
      int kc = idx >> 5, pq = idx & 31;
      float4 xv = *(const float4*)(xb + (size_t)(c0 + kc) * Ppad + p0 + pq * 4);
      *(float4*)&xs[kc][pq * 4] = xv;
    }
#pragma unroll
    for (int u = 0; u < 4; u++) {
      int idx = tid + u * 256;               // 1024 scalars
      int oo = idx >> 4, kc = idx & 15;
      wsT[kc][oo] = (o0 + oo < O) ? Wt[(size_t)(o0 + oo) * Cn + c0 + kc] : 0.f;
    }
    __syncthreads();
#pragma unroll
    for (int kc = 0; kc < 16; kc++) {
      float4 xv = *(const float4*)&xs[kc][tp * 4];
      float4 w0 = *(const float4*)&wsT[kc][to * 8];
      float4 w1 = *(const float4*)&wsT[kc][to * 8 + 4];
      float wv_[8] = {w0.x, w0.y, w0.z, w0.w, w1.x, w1.y, w1.z, w1.w};
      float xv_[4] = {xv.x, xv.y, xv.z, xv.w};
#pragma unroll
      for (int u = 0; u < 8; u++)
#pragma unroll
        for (int q = 0; q < 4; q++)
          acc[u][q] = fmaf(wv_[u], xv_[q], acc[u][q]);
    }
    __syncthreads();
  }
  bool full = (p0 + 128 <= Pn);
#pragma unroll
  for (int u = 0; u < 8; u++) {
    int o = o0 + to * 8 + u;
    if (o >= O) break;
    float bb = bias[o];
    float* op = out + ((size_t)b * O + o) * Ppad + p0 + tp * 4;
    if (full) {
      float4 r;
      r.x = acc[u][0] + bb; r.y = acc[u][1] + bb;
      r.z = acc[u][2] + bb; r.w = acc[u][3] + bb;
      *(float4*)op = r;
    } else {
#pragma unroll
      for (int q = 0; q < 4; q++) {
        int p = p0 + tp * 4 + q;
        if (p < Pn) op[q] = acc[u][q] + bb;
      }
    }
  }
}

// --- per-plane 127x127 transpose: dst[j*127+i] = src[i*127+j] ---------------
__global__ __launch_bounds__(256) void k_transpose(const float* __restrict__ src,
                                                   float* __restrict__ dst) {
  __shared__ float t[32][33];
  int plane = blockIdx.y;
  int tx = blockIdx.x & 3, ty = blockIdx.x >> 2;
  const float* sp = src + (size_t)plane * Ppad;
  float* dp = dst + (size_t)plane * Ppad;
  int i0 = ty * 32, j0 = tx * 32;
  int lj = threadIdx.x & 31, li = threadIdx.x >> 5;  // li 0..7
#pragma unroll
  for (int u = 0; u < 4; u++) {
    int i = i0 + li + u * 8, j = j0 + lj;
    if (i < hn && j < hn) t[li + u * 8][lj] = sp[i * wn + j];
  }
  __syncthreads();
#pragma unroll
  for (int u = 0; u < 4; u++) {
    int j = j0 + li + u * 8, i = i0 + lj;
    if (i < hn && j < hn) dp[(size_t)j * hn + i] = t[lj][li + u * 8];
  }
}

// --- raw scores.  COL: e[i,l] = sum_c Q[b,c,i,fix]*K[b,c,l,fix] (diag=-inf)
//                  ROW: e[j,m] = sum_c Q[b,c,fix,j]*K[b,c,fix,m]
// Writes into S rows of length 254 (COL -> [0,127), ROW -> [127,254)). -------
template <bool COL>
__global__ __launch_bounds__(256) void k_score(const float* __restrict__ Q,
                                               const float* __restrict__ K,
                                               float* __restrict__ S, int CH) {
  __shared__ float qs[32][128];
  __shared__ float ks[32][128];
  int fix = blockIdx.x, b = blockIdx.y, tid = threadIdx.x;
  const float* Qb = Q + (size_t)b * CH * Ppad;
  const float* Kb = K + (size_t)b * CH * Ppad;
  int i0 = (tid >> 4) * 8;
  int l0 = (tid & 15) * 8;
  float acc[8][8] = {};
  for (int c0 = 0; c0 < CH; c0 += 32) {
    for (int idx = tid; idx < 32 * 128; idx += 256) {
      int c = idx >> 7, r = idx & 127;
      float qv = 0.f, kv = 0.f;
      if (r < hn) {
        size_t off = COL ? ((size_t)(c0 + c) * Ppad + r * wn + fix)
                         : ((size_t)(c0 + c) * Ppad + fix * wn + r);
        qv = Qb[off];
        kv = Kb[off];
      }
      qs[c][r] = qv;
      ks[c][r] = kv;
    }
    __syncthreads();
#pragma unroll 8
    for (int c = 0; c < 32; c++) {
      float4 q0 = *(const float4*)&qs[c][i0];
      float4 q1 = *(const float4*)&qs[c][i0 + 4];
      float4 k0 = *(const float4*)&ks[c][l0];
      float4 k1 = *(const float4*)&ks[c][l0 + 4];
      float qv_[8] = {q0.x, q0.y, q0.z, q0.w, q1.x, q1.y, q1.z, q1.w};
      float kv_[8] = {k0.x, k0.y, k0.z, k0.w, k1.x, k1.y, k1.z, k1.w};
#pragma unroll
      for (int a = 0; a < 8; a++)
#pragma unroll
        for (int u = 0; u < 8; u++)
          acc[a][u] = fmaf(qv_[a], kv_[u], acc[a][u]);
    }
    __syncthreads();
  }
#pragma unroll
  for (int a = 0; a < 8; a++) {
    int i = i0 + a;
    if (i >= hn) break;
    size_t rowbase = COL ? (((size_t)(b * hn + i) * wn + fix) * Ln)
                         : (((size_t)(b * hn + fix) * wn + i) * Ln + hn);
#pragma unroll
    for (int u = 0; u < 8; u++) {
      int l = l0 + u;
      if (l >= hn) continue;
      float val = acc[a][u];
      if (COL && l == i) val = -INFINITY;
      S[rowbase + l] = val;
    }
  }
}

// --- fused triple softmax over each 254-row: S = softmax(softmax(e)*softmax(ea))
__global__ __launch_bounds__(256) void k_softmax(float* __restrict__ e,
                                                 const float* __restrict__ ea) {
  int lane = threadIdx.x & 63;
  int wv = threadIdx.x >> 6;
  size_t row = (size_t)blockIdx.x * 4 + wv;  // exactly B*Pn rows
  float* ep = e + row * Ln;
  const float* ap = ea + row * Ln;
  float ev[4], av[4];
  bool val[4];
#pragma unroll
  for (int u = 0; u < 4; u++) {
    int t = lane + 64 * u;
    val[u] = t < Ln;
    ev[u] = val[u] ? ep[t] : -INFINITY;
    av[u] = val[u] ? ap[t] : -INFINITY;
  }
  float m1 = wred_max(fmaxf(fmaxf(ev[0], ev[1]), fmaxf(ev[2], ev[3])));
  float m1a = wred_max(fmaxf(fmaxf(av[0], av[1]), fmaxf(av[2], av[3])));
  float pe[4], pa[4], s1 = 0.f, s1a = 0.f;
#pragma unroll
  for (int u = 0; u < 4; u++) {
    pe[u] = val[u] ? __expf(ev[u] - m1) : 0.f;
    pa[u] = val[u] ? __expf(av[u] - m1a) : 0.f;
    s1 += pe[u];
    s1a += pa[u];
  }
  s1 = wred_sum(s1);
  s1a = wred_sum(s1a);
  float inv = 1.f / (s1 * s1a);
  float pr[4];
#pragma unroll
  for (int u = 0; u < 4; u++) pr[u] = val[u] ? pe[u] * pa[u] * inv : -INFINITY;
  float m2 = wred_max(fmaxf(fmaxf(pr[0], pr[1]), fmaxf(pr[2], pr[3])));
  float q2[4], s2 = 0.f;
#pragma unroll
  for (int u = 0; u < 4; u++) {
    q2[u] = val[u] ? __expf(pr[u] - m2) : 0.f;
    s2 += q2[u];
  }
  s2 = wred_sum(s2);
  float r = 1.f / s2;
#pragma unroll
  for (int u = 0; u < 4; u++) {
    int t = lane + 64 * u;
    if (val[u]) ep[t] = q2[u] * r;
  }
}

// --- attention apply. COL: outT[b,c,fix,io] = sum_red S[b,io,fix,red]*vT[b,c,fix*127+red]
//                      ROW: outW[b,c,fix,io] = sum_red S[b,fix,io,127+red]*v[b,c,fix*127+red]
// V is pre-arranged so that (plane + fix*127 + red) is contiguous in red. ----
template <bool COL>
__global__ __launch_bounds__(256) void k_out(const float* __restrict__ S,
                                             const float* __restrict__ V,
                                             float* __restrict__ out) {
  __shared__ float attT[32][128];
  __shared__ float vsT[32][68];
  int fix = blockIdx.x, cblk = blockIdx.y, b = blockIdx.z, tid = threadIdx.x;
  int c0 = cblk * 64;
  int ig = tid & 15, cg = tid >> 4;
  int i0 = ig * 8;
  float acc[4][8] = {};
  for (int rc = 0; rc < 4; rc++) {
    int red0 = rc * 32;
    for (int idx = tid; idx < 32 * 128; idx += 256) {
      int io = idx & 127, rr = idx >> 7;
      int red = red0 + rr;
      float vvv = 0.f;
      if (io < hn && red < hn) {
        size_t a = COL ? (((size_t)(b * hn + io) * wn + fix) * Ln + red)
                       : (((size_t)(b * hn + fix) * wn + io) * Ln + hn + red);
        vvv = S[a];
      }
      attT[rr][io] = vvv;
    }
    for (int idx = tid; idx < 32 * 64; idx += 256) {
      int rr = idx & 31, cc = idx >> 5;
      int red = red0 + rr;
      float vvv = 0.f;
      if (red < hn)
        vvv = V[(size_t)(b * Cn + c0 + cc) * Ppad + fix * wn + red];
      vsT[rr][cc] = vvv;
    }
    __syncthreads();
#pragma unroll 4
    for (int rr = 0; rr < 32; rr++) {
      float4 a0 = *(const float4*)&attT[rr][i0];
      float4 a1 = *(const float4*)&attT[rr][i0 + 4];
      float4 vv = *(const float4*)&vsT[rr][cg * 4];
      float av[8] = {a0.x, a0.y, a0.z, a0.w, a1.x, a1.y, a1.z, a1.w};
      float vc[4] = {vv.x, vv.y, vv.z, vv.w};
#pragma unroll
      for (int u = 0; u < 4; u++)
#pragma unroll
        for (int q = 0; q < 8; q++)
          acc[u][q] = fmaf(vc[u], av[q], acc[u][q]);
    }
    __syncthreads();
  }
#pragma unroll
  for (int u = 0; u < 4; u++) {
    int c = c0 + cg * 4 + u;
    float* op = out + (size_t)(b * Cn + c) * Ppad + (size_t)fix * 127;
#pragma unroll
    for (int q = 0; q < 8; q++) {
      int io = i0 + q;
      if (io < hn) op[io] = acc[u][q];
    }
  }
}

// --- final: out = gamma*(resize(outH)+resize(outW)) + x ---------------------
// oT plane layout [j][i]; oW plane layout [i][j]; both plane stride Ppad.
// Tiled: each block owns a 64x64 output tile of one (b,c) plane and stages
// the needed 33x33 input windows of oT and oW in LDS so every global access
// is contiguous (the old version gathered oT columns at stride 508B ->
// 2.1 TB/s, 26% of peak). Scale 126/255 ~ 0.494 => 64 outputs span <= 33
// inputs per axis; window start rows are {0,31,63,94}, so start+32 <= 126.
__global__ __launch_bounds__(256) void k_final(const float* __restrict__ oT,
                                               const float* __restrict__ oW,
                                               const float* __restrict__ x,
                                               const float* __restrict__ gamma,
                                               float* __restrict__ out) {
  __shared__ float tT[33 * 33];  // tT[lx*33+ly] = oT[(jx0+lx)*127 + iy0+ly]
  __shared__ float tW[33 * 33];  // tW[ly*33+lx] = oW[(iy0+ly)*127 + jx0+lx]
  const float s = 126.0f / 255.0f;
  int tile = blockIdx.x;          // 0..15
  int txi = tile & 3, tyi = tile >> 2;
  int bc = blockIdx.y;            // 0..1023
  int y0o = tyi * 64, x0o = txi * 64;
  int iy0 = (int)(y0o * s);       // input row window start (y axis)
  int jx0 = (int)(x0o * s);       // input col window start (x axis)
  const float* tp_ = oT + (size_t)bc * Ppad;
  const float* wp_ = oW + (size_t)bc * Ppad;
  int tid = threadIdx.x;
  for (int idx = tid; idx < 33 * 33; idx += 256) {
    int r = idx / 33, cc = idx - r * 33;
    tT[idx] = tp_[(jx0 + r) * 127 + iy0 + cc];  // contiguous in cc
    tW[idx] = wp_[(iy0 + r) * 127 + jx0 + cc];  // contiguous in cc
  }
  __syncthreads();
  int lx = tid & 63;              // x within tile (lane -> coalesced)
  int lyb = tid >> 6;             // 0..3
  int xx = x0o + lx;
  float fx = xx * s;
  int x0i = (int)fx;
  float wx = fx - x0i;
  int lx0 = x0i - jx0;
  int lx1 = min(x0i + 1, hn - 1) - jx0;
  float g = gamma[0];
  size_t base = ((size_t)bc << 16);
#pragma unroll
  for (int u = 0; u < 16; u++) {
    int yy = y0o + lyb + 4 * u;
    float fy = yy * s;
    int y0i = (int)fy;
    float wy = fy - y0i;
    int ly0 = y0i - iy0;
    int ly1 = min(y0i + 1, hn - 1) - iy0;
    float hv = (tT[lx0 * 33 + ly0] * (1.f - wy) + tT[lx0 * 33 + ly1] * wy) * (1.f - wx) +
               (tT[lx1 * 33 + ly0] * (1.f - wy) + tT[lx1 * 33 + ly1] * wy) * wx;
    float wv = (tW[ly0 * 33 + lx0] * (1.f - wx) + tW[ly0 * 33 + lx1] * wx) * (1.f - wy) +
               (tW[ly1 * 33 + lx0] * (1.f - wx) + tW[ly1 * 33 + lx1] * wx) * wy;
    size_t idx = base + (size_t)yy * 256 + xx;
    out[idx] = g * (hv + wv) + x[idx];
  }
}

extern "C" void kernel_launch(void* const* d_in, const int* in_sizes, int n_in,
                              void* d_out, int out_size, void* d_ws, size_t ws_size,
                              hipStream_t stream) {
  const float* x    = (const float*)d_in[0];
  const float* amap = (const float*)d_in[1];
  const float* wdn  = (const float*)d_in[2];
  const float* wq   = (const float*)d_in[3];
  const float* bq   = (const float*)d_in[4];
  const float* wk   = (const float*)d_in[5];
  const float* bk   = (const float*)d_in[6];
  const float* wv   = (const float*)d_in[7];
  const float* bv   = (const float*)d_in[8];
  const float* gamma = (const float*)d_in[9];
  float* out = (float*)d_out;
  float* ws  = (float*)d_ws;

  const size_t PL = (size_t)Bn * Cn * Ppad;   // 16,519,168
  const size_t SL = (size_t)Bn * Pn * Ln;     // 16,387,064
  const size_t QL = (size_t)Bn * CQn * Ppad;  //  2,064,896

  float* xd  = ws;                 // R0: xd -> Saa -> outW
  float* Saa = ws;
  float* oW  = ws;
  float* v   = ws + PL;            // R1
  float* Sqk = ws + 2 * PL;        // R2 (becomes S in-place)
  float* qb  = ws + 2 * PL + SL;   // R3: q|k|a -> outH^T
  float* kb  = qb + QL;
  float* ab  = kb + QL;
  float* oT  = ws + 2 * PL + SL;
  float* vt  = ws + 3 * PL + SL;   // R4: v^T

  k_conv<<<dim3(64, Bn * Cn), 256, 0, stream>>>(x, wdn, xd);
  k_resize_a<<<dim3((Bn * CAn * Pn + 255) / 256), 256, 0, stream>>>(amap, ab);
  k_gemm<<<dim3(127, 1, Bn), 256, 0, stream>>>(wq, bq, xd, qb, CQn);
  k_gemm<<<dim3(127, 1, Bn), 256, 0, stream>>>(wk, bk, xd, kb, CQn);
  k_gemm<<<dim3(127, 4, Bn), 256, 0, stream>>>(wv, bv, xd, v, Cn);
  k_transpose<<<dim3(16, Bn * Cn), 256, 0, stream>>>(v, vt);
  k_score<true><<<dim3(wn, Bn), 256, 0, stream>>>(qb, kb, Sqk, CQn);
  k_score<false><<<dim3(hn, Bn), 256, 0, stream>>>(qb, kb, Sqk, CQn);
  k_score<true><<<dim3(wn, Bn), 256, 0, stream>>>(ab, ab, Saa, CAn);
  k_score<false><<<dim3(hn, Bn), 256, 0, stream>>>(ab, ab, Saa, CAn);
  k_softmax<<<dim3(Bn * Pn / 4), 256, 0, stream>>>(Sqk, Saa);
  k_out<true><<<dim3(wn, 4, Bn), 256, 0, stream>>>(Sqk, vt, oT);
  k_out<false><<<dim3(hn, 4, Bn), 256, 0, stream>>>(Sqk, v, oW);
  k_final<<<dim3(16, Bn * Cn), 256, 0, stream>>>(oT, oW, x, gamma, out);
}

// Round 2
// 1261.216 us; speedup vs baseline: 1.3543x; 1.1659x over previous
//
#include <hip/hip_runtime.h>
#include <math.h>

// ---------------------------------------------------------------------------
// Criss-Cross-Attention pipeline, fp32 correctness-first implementation.
// Shapes: x (4,256,256,256); conv 4x4 s2 VALID -> xd (4,256,127,127)
// q,k: (4,32,127,127); v: (4,256,127,127); a = resize(attn_map) (4,64,127,127)
// scores: per (b,i,j) 254-vector = [col(l=0..126), row(m=0..126)]
// S = softmax( softmax(e_qk) * softmax(e_aa) ); out = attH.v + attW.v
// final: gamma * (resize(outH)+resize(outW)) + x
//
// Workspace layout (floats), planes padded to Ppad=16132 for float4 alignment:
//   R0 [0, PL)            : xd  -> Saa -> outW      (lifetimes disjoint)
//   R1 [PL, 2PL)          : v
//   R2 [2PL, 2PL+SL)      : Sqk -> S (in-place)
//   R3 [2PL+SL, 3PL+SL)   : q | k | a  -> outH^T    (lifetimes disjoint)
//   R4 [3PL+SL, 4PL+SL)   : v^T (per-plane transposed)
// total = 4*PL + SL = 82,463,736 floats = ~330 MB   (assumes ws_size >= this)
// ---------------------------------------------------------------------------

static constexpr int Bn   = 4;
static constexpr int Cn   = 256;
static constexpr int Hn   = 256;
static constexpr int Wn   = 256;
static constexpr int CAn  = 64;
static constexpr int CQn  = 32;
static constexpr int hn   = 127;
static constexpr int wn   = 127;
static constexpr int Pn   = hn * wn;   // 16129
static constexpr int Ppad = 16132;     // padded plane stride (mult of 4)
static constexpr int Ln   = 254;       // concat score length

__device__ __forceinline__ float wred_max(float v) {
#pragma unroll
  for (int o = 32; o > 0; o >>= 1) v = fmaxf(v, __shfl_xor(v, o, 64));
  return v;
}
__device__ __forceinline__ float wred_sum(float v) {
#pragma unroll
  for (int o = 32; o > 0; o >>= 1) v += __shfl_xor(v, o, 64);
  return v;
}

// --- depthwise 4x4 stride-2 conv: x (B,C,256,256) -> xd (B,C,127,127) -------
__global__ __launch_bounds__(256) void k_conv(const float* __restrict__ x,
                                              const float* __restrict__ wd,
                                              float* __restrict__ xd) {
  int p  = blockIdx.x * 256 + threadIdx.x;
  int bc = blockIdx.y;  // b*Cn + c
  if (p >= Pn) return;
  int oy = p / wn, ox = p - oy * wn;
  int c  = bc & (Cn - 1);
  const float* wp = wd + c * 16;
  const float* xp = x + (size_t)bc * (Hn * Wn) + (2 * oy) * Wn + 2 * ox;
  float s = 0.f;
#pragma unroll
  for (int ky = 0; ky < 4; ky++)
#pragma unroll
    for (int kx = 0; kx < 4; kx++)
      s = fmaf(xp[ky * Wn + kx], wp[ky * 4 + kx], s);
  xd[(size_t)bc * Ppad + p] = s;
}

// --- bilinear resize attn_map (B,64,256,256) -> a (B,64,127,127) ------------
__global__ __launch_bounds__(256) void k_resize_a(const float* __restrict__ src,
                                                  float* __restrict__ dst) {
  int idx = blockIdx.x * 256 + threadIdx.x;
  if (idx >= Bn * CAn * Pn) return;
  int p = idx % Pn, bc = idx / Pn;
  int i = p / wn, j = p - i * wn;
  float fy = i * (255.0f / 126.0f);
  float fx = j * (255.0f / 126.0f);
  int y0 = min((int)fy, Hn - 1), x0 = min((int)fx, Wn - 1);
  int y1 = min(y0 + 1, Hn - 1), x1 = min(x0 + 1, Wn - 1);
  float wy = fy - y0, wx = fx - x0;
  const float* sp = src + (size_t)bc * (Hn * Wn);
  float v00 = sp[y0 * Wn + x0], v01 = sp[y0 * Wn + x1];
  float v10 = sp[y1 * Wn + x0], v11 = sp[y1 * Wn + x1];
  dst[(size_t)bc * Ppad + p] =
      (v00 * (1.f - wy) + v10 * wy) * (1.f - wx) +
      (v01 * (1.f - wy) + v11 * wy) * wx;
}

// --- out[b,o,p] = sum_c W[o,c]*xd[b,c,p] + bias[o]  (tile 64o x 128p) -------
__global__ __launch_bounds__(256) void k_gemm(const float* __restrict__ Wt,
                                              const float* __restrict__ bias,
                                              const float* __restrict__ xd,
                                              float* __restrict__ out, int O) {
  __shared__ float xs[16][128];
  __shared__ float wsT[16][64];
  int p0 = blockIdx.x * 128, o0 = blockIdx.y * 64, b = blockIdx.z;
  int tid = threadIdx.x;
  int tp = tid & 31, to = tid >> 5;
  const float* xb = xd + (size_t)b * Cn * Ppad;
  float acc[8][4] = {};
  for (int c0 = 0; c0 < Cn; c0 += 16) {
#pragma unroll
    for (int u = 0; u < 2; u++) {
      int idx = tid + u * 256;               // 512 float4s
      int kc = idx >> 5, pq = idx & 31;
      float4 xv = *(const float4*)(xb + (size_t)(c0 + kc) * Ppad + p0 + pq * 4);
      *(float4*)&xs[kc][pq * 4] = xv;
    }
#pragma unroll
    for (int u = 0; u < 4; u++) {
      int idx = tid + u * 256;               // 1024 scalars
      int oo = idx >> 4, kc = idx & 15;
      wsT[kc][oo] = (o0 + oo < O) ? Wt[(size_t)(o0 + oo) * Cn + c0 + kc] : 0.f;
    }
    __syncthreads();
#pragma unroll
    for (int kc = 0; kc < 16; kc++) {
      float4 xv = *(const float4*)&xs[kc][tp * 4];
      float4 w0 = *(const float4*)&wsT[kc][to * 8];
      float4 w1 = *(const float4*)&wsT[kc][to * 8 + 4];
      float wv_[8] = {w0.x, w0.y, w0.z, w0.w, w1.x, w1.y, w1.z, w1.w};
      float xv_[4] = {xv.x, xv.y, xv.z, xv.w};
#pragma unroll
      for (int u = 0; u < 8; u++)
#pragma unroll
        for (int q = 0; q < 4; q++)
          acc[u][q] = fmaf(wv_[u], xv_[q], acc[u][q]);
    }
    __syncthreads();
  }
  bool full = (p0 + 128 <= Pn);
#pragma unroll
  for (int u = 0; u < 8; u++) {
    int o = o0 + to * 8 + u;
    if (o >= O) break;
    float bb = bias[o];
    float* op = out + ((size_t)b * O + o) * Ppad + p0 + tp * 4;
    if (full) {
      float4 r;
      r.x = acc[u][0] + bb; r.y = acc[u][1] + bb;
      r.z = acc[u][2] + bb; r.w = acc[u][3] + bb;
      *(float4*)op = r;
    } else {
#pragma unroll
      for (int q = 0; q < 4; q++) {
        int p = p0 + tp * 4 + q;
        if (p < Pn) op[q] = acc[u][q] + bb;
      }
    }
  }
}

// --- per-plane 127x127 transpose: dst[j*127+i] = src[i*127+j] ---------------
__global__ __launch_bounds__(256) void k_transpose(const float* __restrict__ src,
                                                   float* __restrict__ dst) {
  __shared__ float t[32][33];
  int plane = blockIdx.y;
  int tx = blockIdx.x & 3, ty = blockIdx.x >> 2;
  const float* sp = src + (size_t)plane * Ppad;
  float* dp = dst + (size_t)plane * Ppad;
  int i0 = ty * 32, j0 = tx * 32;
  int lj = threadIdx.x & 31, li = threadIdx.x >> 5;  // li 0..7
#pragma unroll
  for (int u = 0; u < 4; u++) {
    int i = i0 + li + u * 8, j = j0 + lj;
    if (i < hn && j < hn) t[li + u * 8][lj] = sp[i * wn + j];
  }
  __syncthreads();
#pragma unroll
  for (int u = 0; u < 4; u++) {
    int j = j0 + li + u * 8, i = i0 + lj;
    if (i < hn && j < hn) dp[(size_t)j * hn + i] = t[lj][li + u * 8];
  }
}

// --- raw scores.  COL: e[i,l] = sum_c Q[b,c,i,fix]*K[b,c,l,fix] (diag=-inf)
//                  ROW: e[j,m] = sum_c Q[b,c,fix,j]*K[b,c,fix,m]
// Writes into S rows of length 254 (COL -> [0,127), ROW -> [127,254)). -------
template <bool COL>
__global__ __launch_bounds__(256) void k_score(const float* __restrict__ Q,
                                               const float* __restrict__ K,
                                               float* __restrict__ S, int CH) {
  __shared__ float qs[32][128];
  __shared__ float ks[32][128];
  int fix = blockIdx.x, b = blockIdx.y, tid = threadIdx.x;
  const float* Qb = Q + (size_t)b * CH * Ppad;
  const float* Kb = K + (size_t)b * CH * Ppad;
  int i0 = (tid >> 4) * 8;
  int l0 = (tid & 15) * 8;
  float acc[8][8] = {};
  for (int c0 = 0; c0 < CH; c0 += 32) {
    for (int idx = tid; idx < 32 * 128; idx += 256) {
      int c = idx >> 7, r = idx & 127;
      float qv = 0.f, kv = 0.f;
      if (r < hn) {
        size_t off = COL ? ((size_t)(c0 + c) * Ppad + r * wn + fix)
                         : ((size_t)(c0 + c) * Ppad + fix * wn + r);
        qv = Qb[off];
        kv = Kb[off];
      }
      qs[c][r] = qv;
      ks[c][r] = kv;
    }
    __syncthreads();
#pragma unroll 8
    for (int c = 0; c < 32; c++) {
      float4 q0 = *(const float4*)&qs[c][i0];
      float4 q1 = *(const float4*)&qs[c][i0 + 4];
      float4 k0 = *(const float4*)&ks[c][l0];
      float4 k1 = *(const float4*)&ks[c][l0 + 4];
      float qv_[8] = {q0.x, q0.y, q0.z, q0.w, q1.x, q1.y, q1.z, q1.w};
      float kv_[8] = {k0.x, k0.y, k0.z, k0.w, k1.x, k1.y, k1.z, k1.w};
#pragma unroll
      for (int a = 0; a < 8; a++)
#pragma unroll
        for (int u = 0; u < 8; u++)
          acc[a][u] = fmaf(qv_[a], kv_[u], acc[a][u]);
    }
    __syncthreads();
  }
#pragma unroll
  for (int a = 0; a < 8; a++) {
    int i = i0 + a;
    if (i >= hn) break;
    size_t rowbase = COL ? (((size_t)(b * hn + i) * wn + fix) * Ln)
                         : (((size_t)(b * hn + fix) * wn + i) * Ln + hn);
#pragma unroll
    for (int u = 0; u < 8; u++) {
      int l = l0 + u;
      if (l >= hn) continue;
      float val = acc[a][u];
      if (COL && l == i) val = -INFINITY;
      S[rowbase + l] = val;
    }
  }
}

// --- fused triple softmax over each 254-row: S = softmax(softmax(e)*softmax(ea))
__global__ __launch_bounds__(256) void k_softmax(float* __restrict__ e,
                                                 const float* __restrict__ ea) {
  int lane = threadIdx.x & 63;
  int wv = threadIdx.x >> 6;
  size_t row = (size_t)blockIdx.x * 4 + wv;  // exactly B*Pn rows
  float* ep = e + row * Ln;
  const float* ap = ea + row * Ln;
  float ev[4], av[4];
  bool val[4];
#pragma unroll
  for (int u = 0; u < 4; u++) {
    int t = lane + 64 * u;
    val[u] = t < Ln;
    ev[u] = val[u] ? ep[t] : -INFINITY;
    av[u] = val[u] ? ap[t] : -INFINITY;
  }
  float m1 = wred_max(fmaxf(fmaxf(ev[0], ev[1]), fmaxf(ev[2], ev[3])));
  float m1a = wred_max(fmaxf(fmaxf(av[0], av[1]), fmaxf(av[2], av[3])));
  float pe[4], pa[4], s1 = 0.f, s1a = 0.f;
#pragma unroll
  for (int u = 0; u < 4; u++) {
    pe[u] = val[u] ? __expf(ev[u] - m1) : 0.f;
    pa[u] = val[u] ? __expf(av[u] - m1a) : 0.f;
    s1 += pe[u];
    s1a += pa[u];
  }
  s1 = wred_sum(s1);
  s1a = wred_sum(s1a);
  float inv = 1.f / (s1 * s1a);
  float pr[4];
#pragma unroll
  for (int u = 0; u < 4; u++) pr[u] = val[u] ? pe[u] * pa[u] * inv : -INFINITY;
  float m2 = wred_max(fmaxf(fmaxf(pr[0], pr[1]), fmaxf(pr[2], pr[3])));
  float q2[4], s2 = 0.f;
#pragma unroll
  for (int u = 0; u < 4; u++) {
    q2[u] = val[u] ? __expf(pr[u] - m2) : 0.f;
    s2 += q2[u];
  }
  s2 = wred_sum(s2);
  float r = 1.f / s2;
#pragma unroll
  for (int u = 0; u < 4; u++) {
    int t = lane + 64 * u;
    if (val[u]) ep[t] = q2[u] * r;
  }
}

// --- attention apply. COL: outT[b,c,fix,io] = sum_red S[b,io,fix,red]*vT[b,c,fix*127+red]
//                      ROW: outW[b,c,fix,io] = sum_red S[b,fix,io,127+red]*v[b,c,fix*127+red]
// V is pre-arranged so that (plane + fix*127 + red) is contiguous in red.
// S staging uses red as the fast lane index: S's last dim IS red, so 32
// consecutive lanes read 128B contiguous (the old io-fast order gathered one
// float per cache line -> latency-bound at 17% VALU / 15% HBM).
// attT padded to 132 so the column-wise LDS writes are only 4-way conflicts.
// Compute remap: ig=tid&31 owns 4 io (one float4, distinct addrs), cg=tid>>5
// owns 8 channels (broadcast reads). ----------------------------------------
template <bool COL>
__global__ __launch_bounds__(256) void k_out(const float* __restrict__ S,
                                             const float* __restrict__ V,
                                             float* __restrict__ out) {
  __shared__ float attT[32][132];
  __shared__ float vsT[32][68];
  int fix = blockIdx.x, cblk = blockIdx.y, b = blockIdx.z, tid = threadIdx.x;
  int c0 = cblk * 64;
  int ig = tid & 31, cg = tid >> 5;
  int i0 = ig * 4;
  float acc[8][4] = {};
  for (int rc = 0; rc < 4; rc++) {
    int red0 = rc * 32;
    for (int idx = tid; idx < 32 * 128; idx += 256) {
      int rr = idx & 31, io = idx >> 5;
      int red = red0 + rr;
      float vvv = 0.f;
      if (io < hn && red < hn) {
        size_t a = COL ? (((size_t)(b * hn + io) * wn + fix) * Ln + red)
                       : (((size_t)(b * hn + fix) * wn + io) * Ln + hn + red);
        vvv = S[a];
      }
      attT[rr][io] = vvv;
    }
    for (int idx = tid; idx < 32 * 64; idx += 256) {
      int rr = idx & 31, cc = idx >> 5;
      int red = red0 + rr;
      float vvv = 0.f;
      if (red < hn)
        vvv = V[(size_t)(b * Cn + c0 + cc) * Ppad + fix * wn + red];
      vsT[rr][cc] = vvv;
    }
    __syncthreads();
#pragma unroll 4
    for (int rr = 0; rr < 32; rr++) {
      float4 av4 = *(const float4*)&attT[rr][i0];
      float4 v0 = *(const float4*)&vsT[rr][cg * 8];
      float4 v1 = *(const float4*)&vsT[rr][cg * 8 + 4];
      float av[4] = {av4.x, av4.y, av4.z, av4.w};
      float vc[8] = {v0.x, v0.y, v0.z, v0.w, v1.x, v1.y, v1.z, v1.w};
#pragma unroll
      for (int u = 0; u < 8; u++)
#pragma unroll
        for (int q = 0; q < 4; q++)
          acc[u][q] = fmaf(vc[u], av[q], acc[u][q]);
    }
    __syncthreads();
  }
#pragma unroll
  for (int u = 0; u < 8; u++) {
    int c = c0 + cg * 8 + u;
    float* op = out + (size_t)(b * Cn + c) * Ppad + (size_t)fix * 127;
#pragma unroll
    for (int q = 0; q < 4; q++) {
      int io = i0 + q;
      if (io < hn) op[io] = acc[u][q];
    }
  }
}

// --- final: out = gamma*(resize(outH)+resize(outW)) + x ---------------------
// oT plane layout [j][i]; oW plane layout [i][j]; both plane stride Ppad.
// Tiled: each block owns a 64x64 output tile of one (b,c) plane and stages
// the needed 33x33 input windows of oT and oW in LDS so every global access
// is contiguous. Scale 126/255 ~ 0.494 => 64 outputs span <= 33 inputs per
// axis; window start rows are {0,31,63,94}, so start+32 <= 126.
__global__ __launch_bounds__(256) void k_final(const float* __restrict__ oT,
                                               const float* __restrict__ oW,
                                               const float* __restrict__ x,
                                               const float* __restrict__ gamma,
                                               float* __restrict__ out) {
  __shared__ float tT[33 * 33];  // tT[lx*33+ly] = oT[(jx0+lx)*127 + iy0+ly]
  __shared__ float tW[33 * 33];  // tW[ly*33+lx] = oW[(iy0+ly)*127 + jx0+lx]
  const float s = 126.0f / 255.0f;
  int tile = blockIdx.x;          // 0..15
  int txi = tile & 3, tyi = tile >> 2;
  int bc = blockIdx.y;            // 0..1023
  int y0o = tyi * 64, x0o = txi * 64;
  int iy0 = (int)(y0o * s);       // input row window start (y axis)
  int jx0 = (int)(x0o * s);       // input col window start (x axis)
  const float* tp_ = oT + (size_t)bc * Ppad;
  const float* wp_ = oW + (size_t)bc * Ppad;
  int tid = threadIdx.x;
  for (int idx = tid; idx < 33 * 33; idx += 256) {
    int r = idx / 33, cc = idx - r * 33;
    tT[idx] = tp_[(jx0 + r) * 127 + iy0 + cc];  // contiguous in cc
    tW[idx] = wp_[(iy0 + r) * 127 + jx0 + cc];  // contiguous in cc
  }
  __syncthreads();
  int lx = tid & 63;              // x within tile (lane -> coalesced)
  int lyb = tid >> 6;             // 0..3
  int xx = x0o + lx;
  float fx = xx * s;
  int x0i = (int)fx;
  float wx = fx - x0i;
  int lx0 = x0i - jx0;
  int lx1 = min(x0i + 1, hn - 1) - jx0;
  float g = gamma[0];
  size_t base = ((size_t)bc << 16);
#pragma unroll
  for (int u = 0; u < 16; u++) {
    int yy = y0o + lyb + 4 * u;
    float fy = yy * s;
    int y0i = (int)fy;
    float wy = fy - y0i;
    int ly0 = y0i - iy0;
    int ly1 = min(y0i + 1, hn - 1) - iy0;
    float hv = (tT[lx0 * 33 + ly0] * (1.f - wy) + tT[lx0 * 33 + ly1] * wy) * (1.f - wx) +
               (tT[lx1 * 33 + ly0] * (1.f - wy) + tT[lx1 * 33 + ly1] * wy) * wx;
    float wv = (tW[ly0 * 33 + lx0] * (1.f - wx) + tW[ly0 * 33 + lx1] * wx) * (1.f - wy) +
               (tW[ly1 * 33 + lx0] * (1.f - wx) + tW[ly1 * 33 + lx1] * wx) * wy;
    size_t idx = base + (size_t)yy * 256 + xx;
    out[idx] = g * (hv + wv) + x[idx];
  }
}

extern "C" void kernel_launch(void* const* d_in, const int* in_sizes, int n_in,
                              void* d_out, int out_size, void* d_ws, size_t ws_size,
                              hipStream_t stream) {
  const float* x    = (const float*)d_in[0];
  const float* amap = (const float*)d_in[1];
  const float* wdn  = (const float*)d_in[2];
  const float* wq   = (const float*)d_in[3];
  const float* bq   = (const float*)d_in[4];
  const float* wk   = (const float*)d_in[5];
  const float* bk   = (const float*)d_in[6];
  const float* wv   = (const float*)d_in[7];
  const float* bv   = (const float*)d_in[8];
  const float* gamma = (const float*)d_in[9];
  float* out = (float*)d_out;
  float* ws  = (float*)d_ws;

  const size_t PL = (size_t)Bn * Cn * Ppad;   // 16,519,168
  const size_t SL = (size_t)Bn * Pn * Ln;     // 16,387,064
  const size_t QL = (size_t)Bn * CQn * Ppad;  //  2,064,896

  float* xd  = ws;                 // R0: xd -> Saa -> outW
  float* Saa = ws;
  float* oW  = ws;
  float* v   = ws + PL;            // R1
  float* Sqk = ws + 2 * PL;        // R2 (becomes S in-place)
  float* qb  = ws + 2 * PL + SL;   // R3: q|k|a -> outH^T
  float* kb  = qb + QL;
  float* ab  = kb + QL;
  float* oT  = ws + 2 * PL + SL;
  float* vt  = ws + 3 * PL + SL;   // R4: v^T

  k_conv<<<dim3(64, Bn * Cn), 256, 0, stream>>>(x, wdn, xd);
  k_resize_a<<<dim3((Bn * CAn * Pn + 255) / 256), 256, 0, stream>>>(amap, ab);
  k_gemm<<<dim3(127, 1, Bn), 256, 0, stream>>>(wq, bq, xd, qb, CQn);
  k_gemm<<<dim3(127, 1, Bn), 256, 0, stream>>>(wk, bk, xd, kb, CQn);
  k_gemm<<<dim3(127, 4, Bn), 256, 0, stream>>>(wv, bv, xd, v, Cn);
  k_transpose<<<dim3(16, Bn * Cn), 256, 0, stream>>>(v, vt);
  k_score<true><<<dim3(wn, Bn), 256, 0, stream>>>(qb, kb, Sqk, CQn);
  k_score<false><<<dim3(hn, Bn), 256, 0, stream>>>(qb, kb, Sqk, CQn);
  k_score<true><<<dim3(wn, Bn), 256, 0, stream>>>(ab, ab, Saa, CAn);
  k_score<false><<<dim3(hn, Bn), 256, 0, stream>>>(ab, ab, Saa, CAn);
  k_softmax<<<dim3(Bn * Pn / 4), 256, 0, stream>>>(Sqk, Saa);
  k_out<true><<<dim3(wn, 4, Bn), 256, 0, stream>>>(Sqk, vt, oT);
  k_out<false><<<dim3(hn, 4, Bn), 256, 0, stream>>>(Sqk, v, oW);
  k_final<<<dim3(16, Bn * Cn), 256, 0, stream>>>(oT, oW, x, gamma, out);
}